// Round 11
// baseline (144.096 us; speedup 1.0000x reference)
//
#include <hip/hip_runtime.h>

// RepeatLayers: variable-length repeat_interleave along axis 0.
// Inputs: d_in[0] = encoder_h float32 [N, D], d_in[1] = repeats int32 [N].
// Output: float32 [total_rows, D], total_rows = sum(repeats).
//
// R11: R10's fused spread at CHUNK=1 (one source row per block, 8192 blocks).
//  - minimal work quantum -> HW dispatcher rebalances at 1-row granularity
//  - r==0 blocks (~12%) exit immediately (no prologue, no load)
//  - row load issued before the prefix prologue (overlaps ~900cyc HBM lat)
//  - prologue: int4 reduction over repeats[0..row) + <=3-int remainder;
//    repeats is 32 KB -> L1/L2 resident, aggregate ~4us overlapped.

typedef float nfloat4 __attribute__((ext_vector_type(4)));

#define BLOCK 256

__global__ __launch_bounds__(BLOCK)
void spread_row_kernel(const nfloat4* __restrict__ h,
                       const int* __restrict__ repeats,
                       nfloat4* __restrict__ out,
                       int d4 /* = D/4, == BLOCK */) {
    const int row = blockIdx.x;
    const int t = threadIdx.x;

    const int r = repeats[row];        // broadcast scalar load
    if (r == 0) return;                // uniform: whole block exits

    // ---- issue payload load now; latency overlaps the prologue ----
    const nfloat4 v = h[(size_t)row * d4 + t];

    // ---- obase = sum(repeats[0..row)) ----
    const int nq = row >> 2;           // whole int4 quads
    const int4* rp4 = (const int4*)repeats;
    int local = 0;
    for (int q = t; q < nq; q += BLOCK) {   // <=8 L2-hit int4 loads/thread
        const int4 w = rp4[q];
        local += w.x + w.y + w.z + w.w;
    }
    if (t < (row & 3)) local += repeats[(nq << 2) + t];  // remainder 0..3

    const int lane = t & 63;
    const int wave = t >> 6;
    __shared__ int wpart[BLOCK / 64];
#pragma unroll
    for (int off = 32; off > 0; off >>= 1)
        local += __shfl_down(local, off, 64);
    if (lane == 0) wpart[wave] = local;
    __syncthreads();
    const int obase = wpart[0] + wpart[1] + wpart[2] + wpart[3];

    // ---- r independent contiguous 4 KB row stores ----
    nfloat4* __restrict__ dst = out + (size_t)obase * d4 + t;
    for (int k = 0; k < r; ++k)
        dst[(size_t)k * d4] = v;
}

// Generic fallback if d4 != BLOCK (not hit for this problem's shape).
__global__ __launch_bounds__(BLOCK)
void spread_row_generic_kernel(const nfloat4* __restrict__ h,
                               const int* __restrict__ repeats,
                               nfloat4* __restrict__ out,
                               int d4) {
    const int row = blockIdx.x;
    const int t = threadIdx.x;
    const int r = repeats[row];
    if (r == 0) return;

    const int nq = row >> 2;
    const int4* rp4 = (const int4*)repeats;
    int local = 0;
    for (int q = t; q < nq; q += BLOCK) {
        const int4 w = rp4[q];
        local += w.x + w.y + w.z + w.w;
    }
    if (t < (row & 3)) local += repeats[(nq << 2) + t];

    const int lane = t & 63;
    const int wave = t >> 6;
    __shared__ int wpart[BLOCK / 64];
#pragma unroll
    for (int off = 32; off > 0; off >>= 1)
        local += __shfl_down(local, off, 64);
    if (lane == 0) wpart[wave] = local;
    __syncthreads();
    const int obase = wpart[0] + wpart[1] + wpart[2] + wpart[3];

    for (int i = t; i < d4; i += BLOCK) {
        const nfloat4 v = h[(size_t)row * d4 + i];
        nfloat4* __restrict__ dst = out + (size_t)obase * d4 + i;
        for (int k = 0; k < r; ++k)
            dst[(size_t)k * d4] = v;
    }
}

extern "C" void kernel_launch(void* const* d_in, const int* in_sizes, int n_in,
                              void* d_out, int out_size, void* d_ws, size_t ws_size,
                              hipStream_t stream) {
    const float* encoder_h = (const float*)d_in[0];
    const int*   repeats   = (const int*)d_in[1];
    float*       out       = (float*)d_out;

    const int n = in_sizes[1];            // 8192 source rows
    const int d = in_sizes[0] / n;        // 1024 features
    const int d4 = d / 4;

    if (d4 == BLOCK) {
        spread_row_kernel<<<n, BLOCK, 0, stream>>>(
            (const nfloat4*)encoder_h, repeats, (nfloat4*)out, d4);
    } else {
        spread_row_generic_kernel<<<n, BLOCK, 0, stream>>>(
            (const nfloat4*)encoder_h, repeats, (nfloat4*)out, d4);
    }
}

// Round 12
// 141.650 us; speedup vs baseline: 1.0173x; 1.0173x over previous
//
#include <hip/hip_runtime.h>

// RepeatLayers: variable-length repeat_interleave along axis 0.
// Inputs: d_in[0] = encoder_h float32 [N, D], d_in[1] = repeats int32 [N].
// Output: float32 [total_rows, D], total_rows = sum(repeats).
//
// R12 = R10 verbatim (the measured optimum, 140.9 us).
// Swept and settled:
//  - CHUNK 8/4/2/1 -> 150.2 / 144.1 / 140.9 / 144.1 us: CHUNK=2 optimal.
//  - fused redundant prefix beats separate scan kernel (R6->R7).
//  - HW dispatcher beats SW ticket scheduling (R9 regressed).
//  - plain stores beat nontemporal (R8 regressed).
//  - row loads issued before the prefix prologue (latency overlap) helps.

typedef float nfloat4 __attribute__((ext_vector_type(4)));

#define CHUNK 2
#define BLOCK 256

__global__ __launch_bounds__(BLOCK)
void spread_fused_kernel(const nfloat4* __restrict__ h,
                         const int* __restrict__ repeats,
                         nfloat4* __restrict__ out,
                         int n, int d4 /* = D/4 */) {
    const int c = blockIdx.x;
    const int rbase = c * CHUNK;
    const int t = threadIdx.x;
    const int lane = t & 63;
    const int wave = t >> 6;

    // ---- 1. own repeat counts (one broadcast int2) ----
    int reps[CHUNK];
    if (rbase + CHUNK <= n) {
        const int2 r2 = *(const int2*)(repeats + rbase);
        reps[0] = r2.x; reps[1] = r2.y;
    } else {
#pragma unroll
        for (int j = 0; j < CHUNK; ++j)
            reps[j] = (rbase + j < n) ? repeats[rbase + j] : 0;
    }

    // ---- 2. issue payload row loads NOW (overlap prologue below) ----
    const int i = t;  // d4 == 256 == BLOCK (guarded by launch config)
    nfloat4 v[CHUNK];
#pragma unroll
    for (int j = 0; j < CHUNK; ++j) {
        if (reps[j] > 0)                       // wave-uniform branch
            v[j] = h[(size_t)(rbase + j) * d4 + i];
    }

    // ---- 3. prologue: obase = sum(repeats[0..rbase)), rbase = 2c ----
    __shared__ int wpart[BLOCK / 64];
    int local = 0;
    {
        const int2* rp2 = (const int2*)repeats;
        for (int q = t; q < c; q += BLOCK) {   // <=16 L2-hit int2 loads/thread
            const int2 w = rp2[q];
            local += w.x + w.y;
        }
    }
#pragma unroll
    for (int off = 32; off > 0; off >>= 1)
        local += __shfl_down(local, off, 64);
    if (lane == 0) wpart[wave] = local;
    __syncthreads();
    const int obase = wpart[0] + wpart[1] + wpart[2] + wpart[3];

    int offs[CHUNK];
    offs[0] = obase;
#pragma unroll
    for (int j = 1; j < CHUNK; ++j) offs[j] = offs[j - 1] + reps[j - 1];

    // ---- 4. stores: independent contiguous 4 KB row stores ----
#pragma unroll
    for (int j = 0; j < CHUNK; ++j) {
        const int r = reps[j];
        nfloat4* __restrict__ dst = out + (size_t)offs[j] * d4 + i;
        for (int k = 0; k < r; ++k)
            dst[(size_t)k * d4] = v[j];
    }
}

// Generic fallback if d4 != BLOCK (not hit for this problem's shapes).
__global__ __launch_bounds__(BLOCK)
void spread_fused_generic_kernel(const nfloat4* __restrict__ h,
                                 const int* __restrict__ repeats,
                                 nfloat4* __restrict__ out,
                                 int n, int d4) {
    const int c = blockIdx.x;
    const int rbase = c * CHUNK;
    const int t = threadIdx.x;
    const int lane = t & 63;
    const int wave = t >> 6;

    int reps[CHUNK];
#pragma unroll
    for (int j = 0; j < CHUNK; ++j)
        reps[j] = (rbase + j < n) ? repeats[rbase + j] : 0;

    __shared__ int wpart[BLOCK / 64];
    int local = 0;
    const int2* rp2 = (const int2*)repeats;
    for (int q = t; q < c; q += BLOCK) {
        const int2 w = rp2[q];
        local += w.x + w.y;
    }
#pragma unroll
    for (int off = 32; off > 0; off >>= 1)
        local += __shfl_down(local, off, 64);
    if (lane == 0) wpart[wave] = local;
    __syncthreads();
    const int obase = wpart[0] + wpart[1] + wpart[2] + wpart[3];

    int offs[CHUNK];
    offs[0] = obase;
#pragma unroll
    for (int j = 1; j < CHUNK; ++j) offs[j] = offs[j - 1] + reps[j - 1];

    for (int i = t; i < d4; i += BLOCK) {
        nfloat4 v[CHUNK];
#pragma unroll
        for (int j = 0; j < CHUNK; ++j)
            if (reps[j] > 0) v[j] = h[(size_t)(rbase + j) * d4 + i];
#pragma unroll
        for (int j = 0; j < CHUNK; ++j) {
            const int r = reps[j];
            nfloat4* __restrict__ dst = out + (size_t)offs[j] * d4 + i;
            for (int k = 0; k < r; ++k)
                dst[(size_t)k * d4] = v[j];
        }
    }
}

extern "C" void kernel_launch(void* const* d_in, const int* in_sizes, int n_in,
                              void* d_out, int out_size, void* d_ws, size_t ws_size,
                              hipStream_t stream) {
    const float* encoder_h = (const float*)d_in[0];
    const int*   repeats   = (const int*)d_in[1];
    float*       out       = (float*)d_out;

    const int n = in_sizes[1];            // 8192 source rows
    const int d = in_sizes[0] / n;        // 1024 features
    const int d4 = d / 4;

    const int nblocks = (n + CHUNK - 1) / CHUNK;   // 4096
    if (d4 == BLOCK) {
        spread_fused_kernel<<<nblocks, BLOCK, 0, stream>>>(
            (const nfloat4*)encoder_h, repeats, (nfloat4*)out, n, d4);
    } else {
        spread_fused_generic_kernel<<<nblocks, BLOCK, 0, stream>>>(
            (const nfloat4*)encoder_h, repeats, (nfloat4*)out, n, d4);
    }
}